// Round 12
// baseline (489.373 us; speedup 1.0000x reference)
//
#include <hip/hip_runtime.h>
#include <hip/hip_bf16.h>
#include <math.h>

typedef __bf16 bf16x8 __attribute__((ext_vector_type(8)));
typedef float  f32x4  __attribute__((ext_vector_type(4)));
typedef __hip_bfloat16 bf16;

#define DIM  1024
#define MLPD 4096
#define NB   4
#define SEQ  2048
#define ROWS (NB * SEQ) /* 8192 */

__device__ __forceinline__ void gload_lds16(const void* g, void* l) {
  __builtin_amdgcn_global_load_lds(
      (__attribute__((address_space(1))) void*)(g),
      (__attribute__((address_space(3))) void*)(l), 16, 0, 0);
}

template <int N>
__device__ __forceinline__ void vmw() {
  asm volatile("s_waitcnt vmcnt(%0)" ::"n"(N) : "memory");
}

__device__ __forceinline__ void lgkm0() {
  asm volatile("s_waitcnt lgkmcnt(0)" ::: "memory");
}

__device__ __forceinline__ bf16 to_bf16(float v) { return __float2bfloat16(v); }
__device__ __forceinline__ bf16 to_bf16(bf16 v)  { return v; }

// exact-GELU via A&S 7.1.26 erf approximation (max abs err ~1.5e-7; far
// inside the 0.09 absmax headroom). ~12 VALU + exp vs libm erff's ~30.
__device__ __forceinline__ float gelu_exact_fast(float v) {
  const float x  = v * 0.70710678118654752f;
  const float ax = fabsf(x);
  const float t  = __builtin_amdgcn_rcpf(1.0f + 0.3275911f * ax);
  const float p  = t * (0.254829592f +
                   t * (-0.284496736f +
                   t * (1.421413741f +
                   t * (-1.453152027f + t * 1.061405429f))));
  float erf = 1.0f - p * __expf(-x * x);
  erf = copysignf(erf, x);
  return 0.5f * v * (1.0f + erf);
}

// ---------------------------------------------------------------------------
// Round-12 WAVE-AUTONOMOUS 128x128 GEMM, BK=32, 4 waves (2x2).
// r6-r11 lesson: cooperative staging pays ~35-40% of cycles at all-wave
// convoy points (barrier+drain) under every schedule tried. Fix: each wave
// stages a PRIVATE copy of exactly the halves it reads (A rows wm*64..,
// B rows wn*64..) into its own 16 KiB LDS region (2 bufs x (A 4K | B 4K)).
// ZERO s_barrier in the kernel — sync is per-wave vmcnt FIFO only:
//   prologue: STAGE(buf0,t0) STAGE(buf1,t1)            (16 loads in flight)
//   tile t:   vmw<8> (retires tile t's 8 loads, issued 2 tiles earlier)
//             8x ds_read_b128; lgkmcnt(0);             (reads done)
//             STAGE(buf t&1, t+2);                     (overwrite now safe)
//             16x MFMA
//   tail: no stage at NT-2/NT-1; vmw<0> at NT-1.
// Cost: A,B each fetched 2x per block (L2 absorbs); LDS 64 KiB -> 2
// blocks/CU = 8 independent wave-pipelines (launch_bounds (256,2): 256-VGPR
// budget, no r8-style spill).
// LDS geometry per 4 KiB operand region (r7 algebra, HW-verified 0
// conflicts): 32 row-pairs x 128B, slot s = ((row&1)*4+kc) ^ ((row>>1)&7);
// read addr folds to base + m*1024; staging dest LINEAR, per-lane global
// source applies the inverse swizzle (G21 involution, re-verified:
// read (m,fr,fq) -> global row 16m+fr, kchunk fq).
// EPI: 0=+bias->bf16 | 2=+resid->fp32 | 3=+bias,gelu->bf16
//      4=+bias+resid->fp32 | 5=*scale->bf16
// Requires: M%128==0, N%128==0, K%64==0 (NT even), gx%8==0, gy%8==0.
// ---------------------------------------------------------------------------
template <int EPI>
__global__ __launch_bounds__(256, 2) void gemm128(
    const bf16* __restrict__ A,  long aBatch, int lda,
    const bf16* __restrict__ Bt, long bBatch, int ldb,
    void* __restrict__ Cout,     long cBatch, int ldc,
    const float* __restrict__ bias,
    const float* __restrict__ resid, long rBatch, int ldr,
    int K, float scale)
{
  __shared__ char smem[4][16384];   // 16 KiB private per wave

  // ---- block swizzle: XCD chunking over 8x8 super-tile order
  const int gx = gridDim.x, gy = gridDim.y;
  const int n = gx * gy * gridDim.z;
  const int f = blockIdx.x + gx * (blockIdx.y + gy * blockIdx.z);
  const int o = (f & 7) * (n >> 3) + (f >> 3);   // bijective, n%8==0
  const int sx = gx >> 3;
  int st = o >> 6;
  const int w = o & 63;
  const int spz = sx * (gy >> 3);
  const int bz = st / spz; st -= bz * spz;
  const int sty = st / sx, stx = st - sty * sx;
  const int by = sty * 8 + (w >> 3), bx = stx * 8 + (w & 7);

  const long rowBase = (long)by * 128;
  const long colBase = (long)bx * 128;
  const long ldaB = (long)lda * 2, ldbB = (long)ldb * 2;
  const char* Ag = (const char*)(A + bz * aBatch + rowBase * lda);
  const char* Bg = (const char*)(Bt + bz * bBatch + colBase * ldb);

  const int tid  = threadIdx.x;
  const int lane = tid & 63;
  const int wave = tid >> 6;
  const int wm = wave >> 1, wn = wave & 1;   // 2x2 wave grid, 64x64 each
  const int fr = lane & 15, fq = lane >> 4;

  // fragment read base within the wave's private operand region
  const int fh = fr >> 1;
  const int sA = (((fr & 1) << 2) | fq) ^ (fh & 7);
  const int laneRd = fh * 128 + sA * 16;
  char* wbase = &smem[wave][0];

  // staging: linear dest slot t=li*64+lane; inverse-swizzled global source
  int offA[4], offB[4];
#pragma unroll
  for (int li = 0; li < 4; ++li) {
    const int tt = li * 64 + lane;
    const int rr = tt >> 3;
    const int uu = (tt & 7) ^ (rr & 7);
    const int srow = rr * 2 + (uu >> 2);
    const int skc  = (uu & 3) * 16;
    offA[li] = (wm * 64 + srow) * (int)ldaB + skc;
    offB[li] = (wn * 64 + srow) * (int)ldbB + skc;
  }
  const int dBase = lane * 16;

  const int NT = K >> 5;
  f32x4 acc[4][4] = {};

#define STAGE(P, JB)                                                           \
  do {                                                                         \
    char* _d = wbase + (P) * 8192 + dBase;                                     \
    _Pragma("unroll") for (int li = 0; li < 4; ++li) {                         \
      gload_lds16(Ag + (JB) + offA[li], _d + li * 1024);                       \
      gload_lds16(Bg + (JB) + offB[li], _d + 4096 + li * 1024);                \
    }                                                                          \
  } while (0)

#define TILE(T, P)                                                             \
  do {                                                                         \
    if ((T) == NT - 1) vmw<0>(); else vmw<8>();                                \
    const char* _r = wbase + (P) * 8192 + laneRd;                              \
    bf16x8 av[4], bv[4];                                                       \
    _Pragma("unroll") for (int m = 0; m < 4; ++m)                              \
      av[m] = *(const bf16x8*)(_r + m * 1024);                                 \
    _Pragma("unroll") for (int nn = 0; nn < 4; ++nn)                           \
      bv[nn] = *(const bf16x8*)(_r + 4096 + nn * 1024);                        \
    lgkm0();                                                                   \
    if ((T) + 2 < NT) STAGE(P, ((T) + 2) * 64);                                \
    __builtin_amdgcn_s_setprio(1);                                             \
    _Pragma("unroll") for (int m = 0; m < 4; ++m)                              \
      _Pragma("unroll") for (int nn = 0; nn < 4; ++nn)                         \
        acc[m][nn] = __builtin_amdgcn_mfma_f32_16x16x32_bf16(                  \
            av[m], bv[nn], acc[m][nn], 0, 0, 0);                               \
    __builtin_amdgcn_s_setprio(0);                                             \
  } while (0)

  // prologue: tiles 0,1 into the wave's two private buffers
  STAGE(0, 0);
  STAGE(1, 64);

  for (int t = 0; t < NT; t += 2) {
    TILE(t, 0);
    TILE(t + 1, 1);
  }

#undef STAGE
#undef TILE

  // Epilogue (C/D mapping: col = ..+fr, row = ..+fq*4+e) — r1-verified
#pragma unroll
  for (int m = 0; m < 4; ++m) {
#pragma unroll
    for (int nn = 0; nn < 4; ++nn) {
      const long col = colBase + wn * 64 + nn * 16 + fr;
#pragma unroll
      for (int e = 0; e < 4; ++e) {
        const long r = rowBase + wm * 64 + m * 16 + fq * 4 + e;
        float v = acc[m][nn][e];
        if constexpr (EPI == 0) {
          v += bias[col];
          ((bf16*)Cout)[bz * cBatch + r * ldc + col] = __float2bfloat16(v);
        } else if constexpr (EPI == 2) {
          v += resid[bz * rBatch + r * ldr + col];
          ((float*)Cout)[bz * cBatch + r * ldc + col] = v;
        } else if constexpr (EPI == 3) {
          v += bias[col];
          ((bf16*)Cout)[bz * cBatch + r * ldc + col] =
              __float2bfloat16(gelu_exact_fast(v));
        } else if constexpr (EPI == 4) {
          v += bias[col] + resid[r * (long)ldr + col];
          ((float*)Cout)[bz * cBatch + r * ldc + col] = v;
        } else {  // 5
          ((bf16*)Cout)[bz * cBatch + r * ldc + col] = __float2bfloat16(v * scale);
        }
      }
    }
  }
}

// ---------------------------------------------------------------------------
// LayerNorm over DIM=1024, one block per row, fp32 in -> bf16 out
// ---------------------------------------------------------------------------
__global__ __launch_bounds__(256) void ln_kernel(
    const float* __restrict__ x, const float* __restrict__ gamma,
    const float* __restrict__ beta, bf16* __restrict__ out)
{
  const long row = blockIdx.x;
  const float4 v = ((const float4*)(x + row * DIM))[threadIdx.x];
  float s  = v.x + v.y + v.z + v.w;
  float ss = v.x * v.x + v.y * v.y + v.z * v.z + v.w * v.w;
  const int lane = threadIdx.x & 63, wave = threadIdx.x >> 6;
#pragma unroll
  for (int o = 32; o; o >>= 1) { s += __shfl_xor(s, o); ss += __shfl_xor(ss, o); }
  __shared__ float rs[4], rss[4];
  if (lane == 0) { rs[wave] = s; rss[wave] = ss; }
  __syncthreads();
  s  = rs[0] + rs[1] + rs[2] + rs[3];
  ss = rss[0] + rss[1] + rss[2] + rss[3];
  const float mean = s * (1.0f / DIM);
  const float var  = ss * (1.0f / DIM) - mean * mean;
  const float rstd = rsqrtf(var + 1e-5f);
  const float4 g = ((const float4*)gamma)[threadIdx.x];
  const float4 b = ((const float4*)beta)[threadIdx.x];
  union { bf16 h[4]; uint2 u; } pk;
  pk.h[0] = __float2bfloat16(g.x * (v.x - mean) * rstd + b.x);
  pk.h[1] = __float2bfloat16(g.y * (v.y - mean) * rstd + b.y);
  pk.h[2] = __float2bfloat16(g.z * (v.z - mean) * rstd + b.z);
  pk.h[3] = __float2bfloat16(g.w * (v.w - mean) * rstd + b.w);
  ((uint2*)(out + row * DIM))[threadIdx.x] = pk.u;
}

// ---------------------------------------------------------------------------
// Row softmax over SEQ=2048 bf16 scores, in-place bf16 out (row stride SEQ)
// ---------------------------------------------------------------------------
__global__ __launch_bounds__(256) void softmax_kernel(bf16* __restrict__ scores)
{
  const long row = blockIdx.x;
  bf16* rp = scores + row * (long)SEQ;
  union { bf16 h[8]; uint4 u; } in;
  in.u = ((const uint4*)rp)[threadIdx.x];
  float f[8];
#pragma unroll
  for (int j = 0; j < 8; ++j) f[j] = __bfloat162float(in.h[j]);
  const int lane = threadIdx.x & 63, wave = threadIdx.x >> 6;
  float mx = f[0];
#pragma unroll
  for (int j = 1; j < 8; ++j) mx = fmaxf(mx, f[j]);
#pragma unroll
  for (int o = 32; o; o >>= 1) mx = fmaxf(mx, __shfl_xor(mx, o));
  __shared__ float rm[4], rsum[4];
  if (lane == 0) rm[wave] = mx;
  __syncthreads();
  mx = fmaxf(fmaxf(rm[0], rm[1]), fmaxf(rm[2], rm[3]));
  float sum = 0.0f;
#pragma unroll
  for (int j = 0; j < 8; ++j) { f[j] = expf(f[j] - mx); sum += f[j]; }
#pragma unroll
  for (int o = 32; o; o >>= 1) sum += __shfl_xor(sum, o);
  if (lane == 0) rsum[wave] = sum;
  __syncthreads();
  sum = rsum[0] + rsum[1] + rsum[2] + rsum[3];
  const float inv = 1.0f / sum;
  union { bf16 h[8]; uint4 u; } pk;
#pragma unroll
  for (int j = 0; j < 8; ++j) pk.h[j] = __float2bfloat16(f[j] * inv);
  ((uint4*)rp)[threadIdx.x] = pk.u;
}

// ---------------------------------------------------------------------------
// Tiled transpose + convert to bf16: out[c*ldOut + r] = in[r*ldIn + c]
// ---------------------------------------------------------------------------
template <typename TI>
__global__ __launch_bounds__(256) void transpose_bf16_kernel(
    const TI* __restrict__ in, bf16* __restrict__ out,
    int ldIn, int ldOut, long inBatch, long outBatch)
{
  __shared__ bf16 tile[32][33];
  const long zin  = (long)blockIdx.z * inBatch;
  const long zout = (long)blockIdx.z * outBatch;
  const int c0 = blockIdx.x * 32, r0 = blockIdx.y * 32;
  const int tx = threadIdx.x & 31, ty = threadIdx.x >> 5;  // 32 x 8
#pragma unroll
  for (int i = 0; i < 32; i += 8)
    tile[ty + i][tx] = to_bf16(in[zin + (long)(r0 + ty + i) * ldIn + c0 + tx]);
  __syncthreads();
#pragma unroll
  for (int i = 0; i < 32; i += 8)
    out[zout + (long)(c0 + ty + i) * ldOut + r0 + tx] = tile[tx][ty + i];
}

// concat bq|bk|bv -> bqkv[3072]
__global__ __launch_bounds__(256) void concat3_kernel(
    const float* __restrict__ a, const float* __restrict__ b,
    const float* __restrict__ c, float* __restrict__ o)
{
  const int i = blockIdx.x * 256 + threadIdx.x;
  if (i < DIM) { o[i] = a[i]; o[DIM + i] = b[i]; o[2 * DIM + i] = c[i]; }
}

// ---------------------------------------------------------------------------
extern "C" void kernel_launch(void* const* d_in, const int* in_sizes, int n_in,
                              void* d_out, int out_size, void* d_ws, size_t ws_size,
                              hipStream_t stream) {
  const float* x   = (const float*)d_in[0];
  const float* g1  = (const float*)d_in[1];
  const float* be1 = (const float*)d_in[2];
  const float* g2  = (const float*)d_in[3];
  const float* be2 = (const float*)d_in[4];
  const float* Wq  = (const float*)d_in[5];
  const float* bq  = (const float*)d_in[6];
  const float* Wk  = (const float*)d_in[7];
  const float* bk  = (const float*)d_in[8];
  const float* Wv  = (const float*)d_in[9];
  const float* bv  = (const float*)d_in[10];
  const float* W1  = (const float*)d_in[11];
  const float* b1  = (const float*)d_in[12];
  const float* W2  = (const float*)d_in[13];
  const float* b2  = (const float*)d_in[14];
  float* out = (float*)d_out;

  char* ws = (char*)d_ws;
  bf16* WqkvT = (bf16*)(ws + 0);            // 6 MiB  [3072][1024]
  bf16* W1T   = (bf16*)(ws + (6l << 20));   // 8 MiB  [4096][1024]
  bf16* W2T   = (bf16*)(ws + (14l << 20));  // 8 MiB  [1024][4096]
  float* bqkv = (float*)(ws + (22l << 20)); // 12 KiB
  bf16* h     = (bf16*)(ws + (23l << 20));  // 16 MiB [8192][1024]
  bf16* qkv   = (bf16*)(ws + (39l << 20));  // 48 MiB [8192][3072]
  bf16* vT    = (bf16*)(ws + (87l << 20));  // 16 MiB [4][1024][2048]
  bf16* sc    = (bf16*)(ws + (103l << 20)); // 32 MiB [4][2048][2048] bf16
  bf16* g_act = (bf16*)sc;                  // 64 MiB [8192][4096], sequential reuse

  const dim3 blk(256);

  // weights -> bf16 transposed
  concat3_kernel<<<4, blk, 0, stream>>>(bq, bk, bv, bqkv);
  transpose_bf16_kernel<float><<<dim3(32, 32, 1), blk, 0, stream>>>(
      Wq, WqkvT, DIM, DIM, 0, 0);
  transpose_bf16_kernel<float><<<dim3(32, 32, 1), blk, 0, stream>>>(
      Wk, WqkvT + (long)DIM * DIM, DIM, DIM, 0, 0);
  transpose_bf16_kernel<float><<<dim3(32, 32, 1), blk, 0, stream>>>(
      Wv, WqkvT + 2l * DIM * DIM, DIM, DIM, 0, 0);
  transpose_bf16_kernel<float><<<dim3(128, 32, 1), blk, 0, stream>>>(
      W1, W1T, MLPD, DIM, 0, 0);
  transpose_bf16_kernel<float><<<dim3(32, 128, 1), blk, 0, stream>>>(
      W2, W2T, DIM, MLPD, 0, 0);

  // LN1
  ln_kernel<<<ROWS, blk, 0, stream>>>(x, g1, be1, h);

  // fused QKV: [8192][1024] @ [3072][1024]^T + bqkv -> qkv bf16
  gemm128<0><<<dim3(24, 64, 1), blk, 0, stream>>>(
      h, 0, DIM, WqkvT, 0, DIM, qkv, 0, 3 * DIM,
      bqkv, nullptr, 0, 0, DIM, 1.0f);

  // v slice -> vT per batch
  transpose_bf16_kernel<bf16><<<dim3(32, 64, NB), blk, 0, stream>>>(
      qkv + 2 * DIM, vT, 3 * DIM, SEQ, (long)SEQ * 3 * DIM, (long)DIM * SEQ);

  // scores = q @ k^T * (1/32) -> bf16
  gemm128<5><<<dim3(16, 16, NB), blk, 0, stream>>>(
      qkv, (long)SEQ * 3 * DIM, 3 * DIM, qkv + DIM, (long)SEQ * 3 * DIM, 3 * DIM,
      sc, (long)SEQ * SEQ, SEQ, nullptr, nullptr, 0, 0, DIM, 0.03125f);

  // softmax rows (bf16 in/out, in-place, stride 2048)
  softmax_kernel<<<ROWS, blk, 0, stream>>>(sc);

  // x1 = P @ V + x -> d_out
  gemm128<2><<<dim3(8, 16, NB), blk, 0, stream>>>(
      sc, (long)SEQ * SEQ, SEQ, vT, (long)DIM * SEQ, SEQ,
      out, (long)SEQ * DIM, DIM, nullptr, x, (long)SEQ * DIM, DIM, SEQ, 1.0f);

  // LN2
  ln_kernel<<<ROWS, blk, 0, stream>>>(out, g2, be2, h);

  // MLP1: gelu(h @ W1 + b1) -> g_act bf16
  gemm128<3><<<dim3(32, 64, 1), blk, 0, stream>>>(
      h, 0, DIM, W1T, 0, DIM, g_act, 0, MLPD, b1, nullptr, 0, 0, DIM, 1.0f);

  // MLP2: out = g_act @ W2 + b2 + x1
  gemm128<4><<<dim3(8, 64, 1), blk, 0, stream>>>(
      g_act, 0, MLPD, W2T, 0, MLPD, out, 0, DIM, b2, out, 0, DIM, MLPD, 1.0f);
}

// Round 13
// 372.844 us; speedup vs baseline: 1.3125x; 1.3125x over previous
//
#include <hip/hip_runtime.h>
#include <hip/hip_bf16.h>
#include <math.h>

typedef __bf16 bf16x8 __attribute__((ext_vector_type(8)));
typedef float  f32x4  __attribute__((ext_vector_type(4)));
typedef __hip_bfloat16 bf16;

#define DIM  1024
#define MLPD 4096
#define NB   4
#define SEQ  2048
#define ROWS (NB * SEQ) /* 8192 */

__device__ __forceinline__ void gload_lds16(const void* g, void* l) {
  __builtin_amdgcn_global_load_lds(
      (__attribute__((address_space(1))) void*)(g),
      (__attribute__((address_space(3))) void*)(l), 16, 0, 0);
}

__device__ __forceinline__ void bar() {
  asm volatile("" ::: "memory");
  __builtin_amdgcn_s_barrier();
  asm volatile("" ::: "memory");
}

template <int N>
__device__ __forceinline__ void vmw() {
  asm volatile("s_waitcnt vmcnt(%0)" ::"n"(N) : "memory");
}

__device__ __forceinline__ bf16 to_bf16(float v) { return __float2bfloat16(v); }
__device__ __forceinline__ bf16 to_bf16(bf16 v)  { return v; }

// exact-GELU via A&S 7.1.26 erf approx (max err ~1.5e-7 << 0.09 headroom).
__device__ __forceinline__ float gelu_exact_fast(float v) {
  const float x  = v * 0.70710678118654752f;
  const float ax = fabsf(x);
  const float t  = __builtin_amdgcn_rcpf(1.0f + 0.3275911f * ax);
  const float p  = t * (0.254829592f +
                   t * (-0.284496736f +
                   t * (1.421413741f +
                   t * (-1.453152027f + t * 1.061405429f))));
  float erf = 1.0f - p * __expf(-x * x);
  erf = copysignf(erf, x);
  return 0.5f * v * (1.0f + erf);
}

__device__ __forceinline__ void epi_store(
    int EPI_, void* Cout, long idx, float v, long col,
    const float* bias, const float* resid, long ridx, float scale);

// ---------------------------------------------------------------------------
// Round-13 256x256 8-phase GEMM (m201 template, rederived):
// BK=64, 8 waves (2M x 4N), per-wave output 128x64, 128 KiB dyn-LDS dbuf.
// QUADRANT-INTERLEAVED halves (the r2/r3 bug): A-half mh = rows with
// bit6==mh (= rows wm*128+mh*64.. for BOTH wm) so EVERY wave's phase-mh
// ds_reads hit only half mh; B-half nh = cols with bit5==nh. Half-tile =
// 16 KiB = 2 gload_lds/thread.
// Phase schedule per K-tile j (buf b=j&1), verified FIFO trace:
//  ph1 (q 0,0): ds A0,B0 (12 rd); stage A1(j+1)->b^1; bar;lgkm;MM;bar
//  ph2 (q 0,1): ds B1 (4 rd);     stage A0(j+2)->b;   bar;lgkm;MM;bar
//  ph3 (q 1,1): ds A1 (8 rd);     stage B0(j+2)->b;   bar;lgkm;MM;bar
//  ph4 (q 1,0): no ds (B0 regs live); stage B1(j+2)->b; vmcnt(6); bar;MM;bar
// vmcnt(6) at ph4(j) retires {A0,B0,B1(j+1) [staged ph2-4(j-1)], A1(j+1)
// [ph1(j)]} leaving {A0,B0,B1(j+2)} — every half-tile retired >=1 phase
// before first use, staged 6-7 phases before use (~900 cyc). Overwrite
// safety: A0/B0 LDS-dead after ph1's trailing bar, B1 after ph2, A1(buf^1)
// after ph3(j-1). Prologue: A0,B0,B1,A1(0), A0,B0,B1(1); vmcnt(6); bar.
// Tails: j=NT-2 stages only A1(NT-1), vmcnt(0); j=NT-1 none.
// LDS region layout (r7-verified conflict-free row-pair swizzle per 4KB/2KB
// sub-block): A: [buf 64K][half 16K][wm 8K][kk 4K][pair*128 + s*16],
// s = ((row&1)*4+kc)^((row>>1)&7); B: [buf][32K+ half 16K][wn 4K][kk 2K][..].
// Staging dest LINEAR (d=li*512+tid)*16; source applies inverse swizzle.
// EPI: 0=+bias->bf16 | 3=+bias,gelu->bf16 | 5=*scale->bf16
// Requires: M%256==0, N%256==0, K%64==0, NT>=3, nwg%8==0.
// ---------------------------------------------------------------------------
template <int EPI>
__global__ __launch_bounds__(512, 2) void gemm256(
    const bf16* __restrict__ A,  long aBatch, int lda,
    const bf16* __restrict__ Bt, long bBatch, int ldb,
    void* __restrict__ Cout,     long cBatch, int ldc,
    const float* __restrict__ bias, int K, float scale)
{
  extern __shared__ char smem[];

  // flat bijective XCD swizzle (nwg % 8 == 0)
  const int gx = gridDim.x, gy = gridDim.y;
  int flat = blockIdx.x + gx * (blockIdx.y + gy * blockIdx.z);
  const int nwg = gx * gy * gridDim.z;
  flat = (flat & 7) * (nwg >> 3) + (flat >> 3);
  const int bx = flat % gx;
  const int t2 = flat / gx;
  const int by = t2 % gy;
  const int bz = t2 / gy;

  const long rowBase = (long)by * 256;
  const long colBase = (long)bx * 256;
  const long ldaB = (long)lda * 2, ldbB = (long)ldb * 2;
  const char* Ag = (const char*)(A + bz * aBatch + rowBase * lda);
  const char* Bg = (const char*)(Bt + bz * bBatch + colBase * ldb);

  const int tid  = threadIdx.x;
  const int lane = tid & 63;
  const int wave = tid >> 6;
  const int wm = wave >> 2, wn = wave & 3;
  const int fr = lane & 15, fq = lane >> 4;
  const int fh2 = fr >> 1;
  const int sA = (((fr & 1) << 2) | fq) ^ fh2;
  const int rdCom = fh2 * 128 + sA * 16;

  // staging source offsets (inverse swizzle; li in {0,1})
  long offA[2], offB[2];
#pragma unroll
  for (int li = 0; li < 2; ++li) {
    const int d = li * 512 + tid;
    {
      const int wms = d >> 9, kks = (d >> 8) & 1, w = d & 255;
      const int pr = w >> 3, s = w & 7, u = s ^ (pr & 7);
      offA[li] = (long)(wms * 128 + pr * 2 + (u >> 2)) * ldaB +
                 kks * 64 + (u & 3) * 16;
    }
    {
      const int wns = d >> 8, kkb = (d >> 7) & 1, w = d & 127;
      const int pr = w >> 3, s = w & 7, u = s ^ (pr & 7);
      offB[li] = (long)(wns * 64 + pr * 2 + (u >> 2)) * ldbB +
                 kkb * 64 + (u & 3) * 16;
    }
  }
  const int dstOff = tid * 16;
  const long aHalf = ldaB << 6;   // +64 rows
  const long bHalf = ldbB << 5;   // +32 rows

  const int NT = K >> 6;   // BK=64 -> tile k-byte offset = J*128

  bf16x8 a[4][2], b[2][2][2];
  f32x4 acc[8][4] = {};

#define STG_A(J, mh)                                                           \
  do {                                                                         \
    char* _d = smem + (((J) & 1) << 16) + (mh) * 16384 + dstOff;               \
    const char* _s = Ag + (J) * 128 + (mh) * aHalf;                            \
    gload_lds16(_s + offA[0], _d);                                             \
    gload_lds16(_s + offA[1], _d + 8192);                                      \
  } while (0)

#define STG_B(J, nh)                                                           \
  do {                                                                         \
    char* _d = smem + (((J) & 1) << 16) + 32768 + (nh) * 16384 + dstOff;       \
    const char* _s = Bg + (J) * 128 + (nh) * bHalf;                            \
    gload_lds16(_s + offB[0], _d);                                             \
    gload_lds16(_s + offB[1], _d + 8192);                                      \
  } while (0)

#define LDA(mh, J)                                                             \
  do {                                                                         \
    const char* _b = smem + (((J) & 1) << 16) + (mh) * 16384 + wm * 8192 +     \
                     rdCom;                                                    \
    _Pragma("unroll") for (int m = 0; m < 4; ++m)                              \
      _Pragma("unroll") for (int kk = 0; kk < 2; ++kk)                         \
        a[m][kk] = *(const bf16x8*)(_b + kk * 4096 + m * 1024);                \
  } while (0)

#define LDB(nh, J)                                                             \
  do {                                                                         \
    const char* _b = smem + (((J) & 1) << 16) + 32768 + (nh) * 16384 +         \
                     wn * 4096 + rdCom;                                        \
    _Pragma("unroll") for (int n = 0; n < 2; ++n)                              \
      _Pragma("unroll") for (int kk = 0; kk < 2; ++kk)                         \
        b[nh][n][kk] = *(const bf16x8*)(_b + kk * 2048 + n * 1024);            \
  } while (0)

#define MM(mh, nh)                                                             \
  do {                                                                         \
    __builtin_amdgcn_s_setprio(1);                                             \
    _Pragma("unroll") for (int m = 0; m < 4; ++m)                              \
      _Pragma("unroll") for (int n = 0; n < 2; ++n)                            \
        _Pragma("unroll") for (int kk = 0; kk < 2; ++kk)                       \
          acc[(mh) * 4 + m][(nh) * 2 + n] =                                    \
              __builtin_amdgcn_mfma_f32_16x16x32_bf16(                         \
                  a[m][kk], b[nh][n][kk], acc[(mh) * 4 + m][(nh) * 2 + n],     \
                  0, 0, 0);                                                    \
    __builtin_amdgcn_s_setprio(0);                                             \
  } while (0)

#define LGKM0 asm volatile("s_waitcnt lgkmcnt(0)" ::: "memory")

#define TILE(J, S1, S2, VN)                                                    \
  do {                                                                         \
    LDA(0, J); LDB(0, J);                                                      \
    if (S1) STG_A((J) + 1, 1);                                                 \
    bar(); LGKM0; MM(0, 0); bar();                                             \
    LDB(1, J);                                                                 \
    if (S2) STG_A((J) + 2, 0);                                                 \
    bar(); LGKM0; MM(0, 1); bar();                                             \
    LDA(1, J);                                                                 \
    if (S2) STG_B((J) + 2, 0);                                                 \
    bar(); LGKM0; MM(1, 1); bar();                                             \
    if (S2) STG_B((J) + 2, 1);                                                 \
    vmw<VN>(); bar(); MM(1, 0); bar();                                         \
  } while (0)

  // prologue: A0,B0,B1,A1(0) | A0,B0,B1(1); vmcnt(6) retires tile 0.
  STG_A(0, 0); STG_B(0, 0); STG_B(0, 1); STG_A(0, 1);
  STG_A(1, 0); STG_B(1, 0); STG_B(1, 1);
  vmw<6>(); bar();

  for (int j = 0; j < NT - 2; ++j) TILE(j, true, true, 6);
  TILE(NT - 2, true, false, 0);
  TILE(NT - 1, false, false, 63);

#undef STG_A
#undef STG_B
#undef LDA
#undef LDB
#undef MM
#undef TILE

  // Epilogue: row = rowBase+wm*128+mh*64+m*16+fq*4+e; col = colBase+wn*64+
  // nh*32+n*16+fr (r1-verified C/D mapping).
#pragma unroll
  for (int mh = 0; mh < 2; ++mh)
#pragma unroll
    for (int m = 0; m < 4; ++m)
#pragma unroll
      for (int nh = 0; nh < 2; ++nh)
#pragma unroll
        for (int n = 0; n < 2; ++n) {
          const long col = colBase + wn * 64 + nh * 32 + n * 16 + fr;
#pragma unroll
          for (int e = 0; e < 4; ++e) {
            const long r = rowBase + wm * 128 + mh * 64 + m * 16 + fq * 4 + e;
            float v = acc[mh * 4 + m][nh * 2 + n][e];
            if constexpr (EPI == 0) {
              v += bias[col];
              ((bf16*)Cout)[bz * cBatch + r * ldc + col] = __float2bfloat16(v);
            } else if constexpr (EPI == 3) {
              v += bias[col];
              ((bf16*)Cout)[bz * cBatch + r * ldc + col] =
                  __float2bfloat16(gelu_exact_fast(v));
            } else {  // 5
              ((bf16*)Cout)[bz * cBatch + r * ldc + col] =
                  __float2bfloat16(v * scale);
            }
          }
        }
}

// ---------------------------------------------------------------------------
// r10 128x128 GEMM (kept for PV / MLP2 where 256^2 grids would half-fill):
// BK=32, 4 waves, 32 KiB dbuf, period-2 drains, conflict-free row-pair LDS.
// EPI: 2=+resid->fp32 | 4=+bias+resid->fp32
// ---------------------------------------------------------------------------
template <int EPI>
__global__ __launch_bounds__(256, 4) void gemm128(
    const bf16* __restrict__ A,  long aBatch, int lda,
    const bf16* __restrict__ Bt, long bBatch, int ldb,
    void* __restrict__ Cout,     long cBatch, int ldc,
    const float* __restrict__ bias,
    const float* __restrict__ resid, long rBatch, int ldr,
    int K, float scale)
{
  __shared__ char smem[2][16384];

  const int gx = gridDim.x, gy = gridDim.y;
  const int n = gx * gy * gridDim.z;
  const int f = blockIdx.x + gx * (blockIdx.y + gy * blockIdx.z);
  const int o = (f & 7) * (n >> 3) + (f >> 3);
  const int sx = gx >> 3;
  int st = o >> 6;
  const int w = o & 63;
  const int spz = sx * (gy >> 3);
  const int bz = st / spz; st -= bz * spz;
  const int sty = st / sx, stx = st - sty * sx;
  const int by = sty * 8 + (w >> 3), bx = stx * 8 + (w & 7);

  const long rowBase = (long)by * 128;
  const long colBase = (long)bx * 128;
  const long ldaB = (long)lda * 2, ldbB = (long)ldb * 2;
  const char* Ag = (const char*)(A + bz * aBatch + rowBase * lda);
  const char* Bg = (const char*)(Bt + bz * bBatch + colBase * ldb);

  const int tid  = threadIdx.x;
  const int lane = tid & 63;
  const int wave = tid >> 6;
  const int wm = wave >> 1, wn = wave & 1;
  const int fr = lane & 15, fq = lane >> 4;

  const int fh = fr >> 1;
  const int sA = (((fr & 1) << 2) | fq) ^ fh;
  const int laneRd = fh * 128 + sA * 16;
  const int abase = wm * 4096 + laneRd;
  const int bbase = 8192 + wn * 4096 + laneRd;

  const int t0   = wave * 128 + lane;
  const int r2   = t0 >> 3;
  const int u0   = (t0 & 7) ^ (r2 & 7);
  const int row0 = r2 * 2 + (u0 >> 2);
  const int kc0  = u0 & 3;
  const char* aSrc0 = Ag + (long)row0 * ldaB + kc0 * 16;
  const char* aSrc1 = aSrc0 + 16 * ldaB;
  const char* bSrc0 = Bg + (long)row0 * ldbB + kc0 * 16;
  const char* bSrc1 = bSrc0 + 16 * ldbB;
  const int doff = wave * 2048 + lane * 16;

  const int NT = K >> 5;
  f32x4 acc[4][4] = {};

#define STAGE(WB)                                                              \
  do {                                                                         \
    gload_lds16(aSrc0, &smem[WB][doff]);                                       \
    gload_lds16(aSrc1, &smem[WB][doff + 1024]);                                \
    gload_lds16(bSrc0, &smem[WB][8192 + doff]);                                \
    gload_lds16(bSrc1, &smem[WB][8192 + doff + 1024]);                         \
    aSrc0 += 64; aSrc1 += 64; bSrc0 += 64; bSrc1 += 64;                        \
  } while (0)

#define READMM(RB)                                                             \
  do {                                                                         \
    const char* _r = &smem[RB][0];                                             \
    bf16x8 av[4], bv[4];                                                       \
    _Pragma("unroll") for (int m = 0; m < 4; ++m)                              \
      av[m] = *(const bf16x8*)(_r + abase + m * 1024);                         \
    _Pragma("unroll") for (int nn = 0; nn < 4; ++nn)                           \
      bv[nn] = *(const bf16x8*)(_r + bbase + nn * 1024);                       \
    __builtin_amdgcn_s_setprio(1);                                             \
    _Pragma("unroll") for (int m = 0; m < 4; ++m)                              \
      _Pragma("unroll") for (int nn = 0; nn < 4; ++nn)                         \
        acc[m][nn] = __builtin_amdgcn_mfma_f32_16x16x32_bf16(                  \
            av[m], bv[nn], acc[m][nn], 0, 0, 0);                               \
    __builtin_amdgcn_s_setprio(0);                                             \
  } while (0)

  for (int t = 0; t < NT; t += 2) {
    STAGE(0);
    STAGE(1);
    vmw<0>(); bar();
    READMM(0);
    READMM(1);
    bar();
  }

#undef STAGE
#undef READMM

#pragma unroll
  for (int m = 0; m < 4; ++m) {
#pragma unroll
    for (int nn = 0; nn < 4; ++nn) {
      const long col = colBase + wn * 64 + nn * 16 + fr;
#pragma unroll
      for (int e = 0; e < 4; ++e) {
        const long r = rowBase + wm * 64 + m * 16 + fq * 4 + e;
        float v = acc[m][nn][e];
        if constexpr (EPI == 2) {
          v += resid[bz * rBatch + r * ldr + col];
          ((float*)Cout)[bz * cBatch + r * ldc + col] = v;
        } else {  // 4
          v += bias[col] + resid[r * (long)ldr + col];
          ((float*)Cout)[bz * cBatch + r * ldc + col] = v;
        }
      }
    }
  }
}

// ---------------------------------------------------------------------------
__global__ __launch_bounds__(256) void ln_kernel(
    const float* __restrict__ x, const float* __restrict__ gamma,
    const float* __restrict__ beta, bf16* __restrict__ out)
{
  const long row = blockIdx.x;
  const float4 v = ((const float4*)(x + row * DIM))[threadIdx.x];
  float s  = v.x + v.y + v.z + v.w;
  float ss = v.x * v.x + v.y * v.y + v.z * v.z + v.w * v.w;
  const int lane = threadIdx.x & 63, wave = threadIdx.x >> 6;
#pragma unroll
  for (int o = 32; o; o >>= 1) { s += __shfl_xor(s, o); ss += __shfl_xor(ss, o); }
  __shared__ float rs[4], rss[4];
  if (lane == 0) { rs[wave] = s; rss[wave] = ss; }
  __syncthreads();
  s  = rs[0] + rs[1] + rs[2] + rs[3];
  ss = rss[0] + rss[1] + rss[2] + rss[3];
  const float mean = s * (1.0f / DIM);
  const float var  = ss * (1.0f / DIM) - mean * mean;
  const float rstd = rsqrtf(var + 1e-5f);
  const float4 g = ((const float4*)gamma)[threadIdx.x];
  const float4 b = ((const float4*)beta)[threadIdx.x];
  union { bf16 h[4]; uint2 u; } pk;
  pk.h[0] = __float2bfloat16(g.x * (v.x - mean) * rstd + b.x);
  pk.h[1] = __float2bfloat16(g.y * (v.y - mean) * rstd + b.y);
  pk.h[2] = __float2bfloat16(g.z * (v.z - mean) * rstd + b.z);
  pk.h[3] = __float2bfloat16(g.w * (v.w - mean) * rstd + b.w);
  ((uint2*)(out + row * DIM))[threadIdx.x] = pk.u;
}

// ---------------------------------------------------------------------------
__global__ __launch_bounds__(256) void softmax_kernel(bf16* __restrict__ scores)
{
  const long row = blockIdx.x;
  bf16* rp = scores + row * (long)SEQ;
  union { bf16 h[8]; uint4 u; } in;
  in.u = ((const uint4*)rp)[threadIdx.x];
  float f[8];
#pragma unroll
  for (int j = 0; j < 8; ++j) f[j] = __bfloat162float(in.h[j]);
  const int lane = threadIdx.x & 63, wave = threadIdx.x >> 6;
  float mx = f[0];
#pragma unroll
  for (int j = 1; j < 8; ++j) mx = fmaxf(mx, f[j]);
#pragma unroll
  for (int o = 32; o; o >>= 1) mx = fmaxf(mx, __shfl_xor(mx, o));
  __shared__ float rm[4], rsum[4];
  if (lane == 0) rm[wave] = mx;
  __syncthreads();
  mx = fmaxf(fmaxf(rm[0], rm[1]), fmaxf(rm[2], rm[3]));
  float sum = 0.0f;
#pragma unroll
  for (int j = 0; j < 8; ++j) { f[j] = expf(f[j] - mx); sum += f[j]; }
#pragma unroll
  for (int o = 32; o; o >>= 1) sum += __shfl_xor(sum, o);
  if (lane == 0) rsum[wave] = sum;
  __syncthreads();
  sum = rsum[0] + rsum[1] + rsum[2] + rsum[3];
  const float inv = 1.0f / sum;
  union { bf16 h[8]; uint4 u; } pk;
#pragma unroll
  for (int j = 0; j < 8; ++j) pk.h[j] = __float2bfloat16(f[j] * inv);
  ((uint4*)rp)[threadIdx.x] = pk.u;
}

// ---------------------------------------------------------------------------
template <typename TI>
__global__ __launch_bounds__(256) void transpose_bf16_kernel(
    const TI* __restrict__ in, bf16* __restrict__ out,
    int ldIn, int ldOut, long inBatch, long outBatch)
{
  __shared__ bf16 tile[32][33];
  const long zin  = (long)blockIdx.z * inBatch;
  const long zout = (long)blockIdx.z * outBatch;
  const int c0 = blockIdx.x * 32, r0 = blockIdx.y * 32;
  const int tx = threadIdx.x & 31, ty = threadIdx.x >> 5;
#pragma unroll
  for (int i = 0; i < 32; i += 8)
    tile[ty + i][tx] = to_bf16(in[zin + (long)(r0 + ty + i) * ldIn + c0 + tx]);
  __syncthreads();
#pragma unroll
  for (int i = 0; i < 32; i += 8)
    out[zout + (long)(c0 + ty + i) * ldOut + r0 + tx] = tile[tx][ty + i];
}

__global__ __launch_bounds__(256) void concat3_kernel(
    const float* __restrict__ a, const float* __restrict__ b,
    const float* __restrict__ c, float* __restrict__ o)
{
  const int i = blockIdx.x * 256 + threadIdx.x;
  if (i < DIM) { o[i] = a[i]; o[DIM + i] = b[i]; o[2 * DIM + i] = c[i]; }
}

// ---------------------------------------------------------------------------
extern "C" void kernel_launch(void* const* d_in, const int* in_sizes, int n_in,
                              void* d_out, int out_size, void* d_ws, size_t ws_size,
                              hipStream_t stream) {
  const float* x   = (const float*)d_in[0];
  const float* g1  = (const float*)d_in[1];
  const float* be1 = (const float*)d_in[2];
  const float* g2  = (const float*)d_in[3];
  const float* be2 = (const float*)d_in[4];
  const float* Wq  = (const float*)d_in[5];
  const float* bq  = (const float*)d_in[6];
  const float* Wk  = (const float*)d_in[7];
  const float* bk  = (const float*)d_in[8];
  const float* Wv  = (const float*)d_in[9];
  const float* bv  = (const float*)d_in[10];
  const float* W1  = (const float*)d_in[11];
  const float* b1  = (const float*)d_in[12];
  const float* W2  = (const float*)d_in[13];
  const float* b2  = (const float*)d_in[14];
  float* out = (float*)d_out;

  char* ws = (char*)d_ws;
  bf16* WqkvT = (bf16*)(ws + 0);            // 6 MiB  [3072][1024]
  bf16* W1T   = (bf16*)(ws + (6l << 20));   // 8 MiB  [4096][1024]
  bf16* W2T   = (bf16*)(ws + (14l << 20));  // 8 MiB  [1024][4096]
  float* bqkv = (float*)(ws + (22l << 20)); // 12 KiB
  bf16* h     = (bf16*)(ws + (23l << 20));  // 16 MiB [8192][1024]
  bf16* qkv   = (bf16*)(ws + (39l << 20));  // 48 MiB [8192][3072]
  bf16* vT    = (bf16*)(ws + (87l << 20));  // 16 MiB [4][1024][2048]
  bf16* sc    = (bf16*)(ws + (103l << 20)); // 32 MiB [4][2048][2048] bf16
  bf16* g_act = (bf16*)sc;                  // 64 MiB [8192][4096], seq. reuse

  const int SMEM = 131072;
  hipFuncSetAttribute(reinterpret_cast<const void*>(&gemm256<0>),
                      hipFuncAttributeMaxDynamicSharedMemorySize, SMEM);
  hipFuncSetAttribute(reinterpret_cast<const void*>(&gemm256<3>),
                      hipFuncAttributeMaxDynamicSharedMemorySize, SMEM);
  hipFuncSetAttribute(reinterpret_cast<const void*>(&gemm256<5>),
                      hipFuncAttributeMaxDynamicSharedMemorySize, SMEM);

  const dim3 blk(256), gblk(512);

  concat3_kernel<<<4, blk, 0, stream>>>(bq, bk, bv, bqkv);
  transpose_bf16_kernel<float><<<dim3(32, 32, 1), blk, 0, stream>>>(
      Wq, WqkvT, DIM, DIM, 0, 0);
  transpose_bf16_kernel<float><<<dim3(32, 32, 1), blk, 0, stream>>>(
      Wk, WqkvT + (long)DIM * DIM, DIM, DIM, 0, 0);
  transpose_bf16_kernel<float><<<dim3(32, 32, 1), blk, 0, stream>>>(
      Wv, WqkvT + 2l * DIM * DIM, DIM, DIM, 0, 0);
  transpose_bf16_kernel<float><<<dim3(128, 32, 1), blk, 0, stream>>>(
      W1, W1T, MLPD, DIM, 0, 0);
  transpose_bf16_kernel<float><<<dim3(32, 128, 1), blk, 0, stream>>>(
      W2, W2T, DIM, MLPD, 0, 0);

  // LN1
  ln_kernel<<<ROWS, blk, 0, stream>>>(x, g1, be1, h);

  // fused QKV (256^2 8-phase): 12x32 = 384 wg
  gemm256<0><<<dim3(12, 32, 1), gblk, SMEM, stream>>>(
      h, 0, DIM, WqkvT, 0, DIM, qkv, 0, 3 * DIM, bqkv, DIM, 1.0f);

  // v slice -> vT per batch
  transpose_bf16_kernel<bf16><<<dim3(32, 64, NB), blk, 0, stream>>>(
      qkv + 2 * DIM, vT, 3 * DIM, SEQ, (long)SEQ * 3 * DIM, (long)DIM * SEQ);

  // scores = q @ k^T * (1/32) -> bf16 (256^2): 8x8x4 = 256 wg
  gemm256<5><<<dim3(8, 8, NB), gblk, SMEM, stream>>>(
      qkv, (long)SEQ * 3 * DIM, 3 * DIM, qkv + DIM, (long)SEQ * 3 * DIM,
      3 * DIM, sc, (long)SEQ * SEQ, SEQ, nullptr, DIM, 0.03125f);

  // softmax rows (bf16 in/out, in-place)
  softmax_kernel<<<ROWS, blk, 0, stream>>>(sc);

  // x1 = P @ V + x -> d_out (gemm128: 8x16x4 = 512 wg)
  gemm128<2><<<dim3(8, 16, NB), blk, 0, stream>>>(
      sc, (long)SEQ * SEQ, SEQ, vT, (long)DIM * SEQ, SEQ,
      out, (long)SEQ * DIM, DIM, nullptr, x, (long)SEQ * DIM, DIM, SEQ, 1.0f);

  // LN2
  ln_kernel<<<ROWS, blk, 0, stream>>>(out, g2, be2, h);

  // MLP1 (256^2 8-phase): 16x32 = 512 wg
  gemm256<3><<<dim3(16, 32, 1), gblk, SMEM, stream>>>(
      h, 0, DIM, W1T, 0, DIM, g_act, 0, MLPD, b1, DIM, 1.0f);

  // MLP2 (gemm128): 8x64 = 512 wg
  gemm128<4><<<dim3(8, 64, 1), blk, 0, stream>>>(
      g_act, 0, MLPD, W2T, 0, MLPD, out, 0, DIM, b2, out, 0, DIM, MLPD, 1.0f);
}